// Round 6
// baseline (406.829 us; speedup 1.0000x reference)
//
#include <hip/hip_runtime.h>
#include <hip/hip_cooperative_groups.h>
#include <stdint.h>
#include <math.h>

namespace cg = cooperative_groups;

#define HIST_WORDS8 16384          // uint32 words, 4 packed uint8 bins each (64 KB)

typedef float f4 __attribute__((ext_vector_type(4)));

// ws layout (uint32 words):
//   [0 .. 1023]     slots: 512 float2 (mn,mx) per minmax block; [0,256)=x, [256,512)=y
//   [1024 .. 1279]  csum[256] (col sums; zeroed by hist_kernel block 0)
//   [1280 .. 2815]  dslots: 256*3 doubles (per-row mi, hx, hy partials)
//   [4096 .. 69631] ghist (atomic-fallback path only; aliases partials region start)
//   [4096 ...]      partials: nblk * 16384 words (packed uint8 per-block hists)

__device__ __forceinline__ void mm4(f4 a, float& mn, float& mx){
    mn = fminf(mn, fminf(fminf(a[0], a[1]), fminf(a[2], a[3])));
    mx = fmaxf(mx, fmaxf(fmaxf(a[0], a[1]), fmaxf(a[2], a[3])));
}

// Blocks [0,nblk_per) scan x; [nblk_per, 2*nblk_per) scan y. Contiguous segments.
__global__ void __launch_bounds__(1024)
minmax_kernel(const f4* __restrict__ x, const f4* __restrict__ y,
              float2* __restrict__ slots, int n4, int nblk_per){
    int isy = (blockIdx.x >= (unsigned)nblk_per) ? 1 : 0;
    const f4* __restrict__ src = isy ? y : x;
    int bid = blockIdx.x - isy * nblk_per;
    int seg = n4 / nblk_per;
    int base = bid * seg;
    const int chunk = 1024 * 8;
    float mn = INFINITY, mx = -INFINITY;
    int off = 0;
    for (; off + chunk <= seg; off += chunk){
        const f4* p = src + base + off + threadIdx.x;
        f4 v0 = p[0],        v1 = p[1024],     v2 = p[2 * 1024], v3 = p[3 * 1024];
        f4 v4 = p[4 * 1024], v5 = p[5 * 1024], v6 = p[6 * 1024], v7 = p[7 * 1024];
        mm4(v0, mn, mx); mm4(v1, mn, mx); mm4(v2, mn, mx); mm4(v3, mn, mx);
        mm4(v4, mn, mx); mm4(v5, mn, mx); mm4(v6, mn, mx); mm4(v7, mn, mx);
    }
    for (int i = base + off + threadIdx.x; i < base + seg; i += 1024) mm4(src[i], mn, mx);
    if (bid == nblk_per - 1)
        for (int i = nblk_per * seg + threadIdx.x; i < n4; i += 1024) mm4(src[i], mn, mx);

    #pragma unroll
    for (int o = 32; o > 0; o >>= 1){
        mn = fminf(mn, __shfl_down(mn, o, 64));
        mx = fmaxf(mx, __shfl_down(mx, o, 64));
    }
    __shared__ float smn[16], smx[16];
    int lane = threadIdx.x & 63, wid = threadIdx.x >> 6;
    if (lane == 0){ smn[wid] = mn; smx[wid] = mx; }
    __syncthreads();
    if (threadIdx.x == 0){
        for (int w = 1; w < 16; ++w){ mn = fminf(mn, smn[w]); mx = fmaxf(mx, smx[w]); }
        slots[blockIdx.x] = make_float2(mn, mx);
    }
}

__device__ __forceinline__ void bin_pair(float vx, float vy,
                                         float mnx, float sx, float mny, float sy,
                                         uint32_t* lh){
    int ix = (int)floorf((vx - mnx) * sx);
    int iy = (int)floorf((vy - mny) * sy);
    ix = ix < 0 ? 0 : (ix > 255 ? 255 : ix);
    iy = iy < 0 ? 0 : (iy > 255 ? 255 : iy);
    uint32_t bin = ((uint32_t)ix << 8) | (uint32_t)iy;
    atomicAdd(&lh[bin >> 2], 1u << ((bin & 3u) * 8u));
}

__device__ __forceinline__ void bin4(f4 a, f4 b,
                                     float mnx, float sx, float mny, float sy,
                                     uint32_t* lh){
    bin_pair(a[0], b[0], mnx, sx, mny, sy, lh);
    bin_pair(a[1], b[1], mnx, sx, mny, sy, lh);
    bin_pair(a[2], b[2], mnx, sx, mny, sy, lh);
    bin_pair(a[3], b[3], mnx, sx, mny, sy, lh);
}

__global__ void __launch_bounds__(1024)
hist_kernel(const f4* __restrict__ x, const f4* __restrict__ y,
            const float2* __restrict__ slots, uint32_t* __restrict__ csum,
            uint32_t* __restrict__ out32, int n4, int atomic_flush){
    __shared__ uint32_t lh[HIST_WORDS8];   // 64 KB
    int t = threadIdx.x;
    if (blockIdx.x == 0 && t < 256) csum[t] = 0u;   // zero for K3 (kernel-boundary flush)

    // ---- derive global min/max from the 512 slots (reuse lh as scratch) ----
    float mnx, sx, mny, sy;
    {
        float mn = INFINITY, mx = -INFINITY;
        if (t < 512){ float2 s = slots[t]; mn = s.x; mx = s.y; }
        #pragma unroll
        for (int o = 32; o > 0; o >>= 1){
            mn = fminf(mn, __shfl_down(mn, o, 64));
            mx = fmaxf(mx, __shfl_down(mx, o, 64));
        }
        int lane = t & 63, wid = t >> 6;
        if (lane == 0 && wid < 8){ lh[2*wid] = __float_as_uint(mn); lh[2*wid+1] = __float_as_uint(mx); }
        __syncthreads();
        if (t == 0){
            float a = fminf(fminf(__uint_as_float(lh[0]),  __uint_as_float(lh[2])),
                            fminf(__uint_as_float(lh[4]),  __uint_as_float(lh[6])));
            float b = fmaxf(fmaxf(__uint_as_float(lh[1]),  __uint_as_float(lh[3])),
                            fmaxf(__uint_as_float(lh[5]),  __uint_as_float(lh[7])));
            float c = fminf(fminf(__uint_as_float(lh[8]),  __uint_as_float(lh[10])),
                            fminf(__uint_as_float(lh[12]), __uint_as_float(lh[14])));
            float d = fmaxf(fmaxf(__uint_as_float(lh[9]),  __uint_as_float(lh[11])),
                            fmaxf(__uint_as_float(lh[13]), __uint_as_float(lh[15])));
            lh[16] = __float_as_uint(a); lh[17] = __float_as_uint(b);
            lh[18] = __float_as_uint(c); lh[19] = __float_as_uint(d);
        }
        __syncthreads();
        mnx = __uint_as_float(lh[16]);
        sx  = 256.0f / ((__uint_as_float(lh[17]) - mnx) + 1e-8f);
        mny = __uint_as_float(lh[18]);
        sy  = 256.0f / ((__uint_as_float(lh[19]) - mny) + 1e-8f);
        __syncthreads();   // everyone done reading lh before zeroing
    }
    for (int w = t; w < HIST_WORDS8; w += blockDim.x) lh[w] = 0u;
    __syncthreads();

    int seg  = n4 / gridDim.x;
    int base = blockIdx.x * seg;
    const int chunk = 1024 * 4;
    int off = 0;
    for (; off + chunk <= seg; off += chunk){
        const f4* px = x + base + off + t;
        const f4* py = y + base + off + t;
        f4 a0 = px[0],        a1 = px[1024], a2 = px[2 * 1024], a3 = px[3 * 1024];
        f4 b0 = py[0],        b1 = py[1024], b2 = py[2 * 1024], b3 = py[3 * 1024];
        bin4(a0, b0, mnx, sx, mny, sy, lh);
        bin4(a1, b1, mnx, sx, mny, sy, lh);
        bin4(a2, b2, mnx, sx, mny, sy, lh);
        bin4(a3, b3, mnx, sx, mny, sy, lh);
    }
    for (int i = base + off + t; i < base + seg; i += 1024)
        bin4(x[i], y[i], mnx, sx, mny, sy, lh);
    if (blockIdx.x == gridDim.x - 1)
        for (int i = gridDim.x * seg + t; i < n4; i += 1024)
            bin4(x[i], y[i], mnx, sx, mny, sy, lh);
    __syncthreads();

    if (!atomic_flush){
        uint4* part = (uint4*)(out32 + (size_t)blockIdx.x * HIST_WORDS8);
        const uint4* l4 = (const uint4*)lh;
        for (int q = t; q < HIST_WORDS8 / 4; q += blockDim.x) part[q] = l4[q];
    } else {
        for (int w = t; w < HIST_WORDS8; w += blockDim.x){
            uint32_t v = lh[w];
            if (v){
                uint32_t c0 = v & 255u, c1 = (v >> 8) & 255u, c2 = (v >> 16) & 255u, c3 = v >> 24;
                if (c0) atomicAdd(&out32[4*w + 0], c0);
                if (c1) atomicAdd(&out32[4*w + 1], c1);
                if (c2) atomicAdd(&out32[4*w + 2], c2);
                if (c3) atomicAdd(&out32[4*w + 3], c3);
            }
        }
    }
}

// Cooperative: 256 blocks x 1024 threads, 1 block/CU. Block b owns hist ROW b,
// kept in registers (thread t<256 holds count for column col(t)). Global 256x256
// hist is never materialized.
__global__ void __launch_bounds__(1024)
reduce_finalize_kernel(const uint32_t* __restrict__ partials,
                       const uint32_t* __restrict__ ghist,
                       uint32_t* __restrict__ csum,
                       double* __restrict__ dslots,
                       float* __restrict__ out, int n, int nparts){
    cg::grid_group grid = cg::this_grid();
    __shared__ uint32_t sm[64][16][16];    // 64 KB; reused as scratch later
    uint32_t* flat = &sm[0][0][0];
    uint32_t* lcs  = flat + 64;            // [64..319]: csum copy
    double*  dred  = (double*)(flat + 512);// 48 doubles at byte 2048
    int t = threadIdx.x;
    int b = blockIdx.x;
    int col = ((t & 15) << 4) | (t >> 4);  // column owned by thread t (t<256)
    uint32_t cnt = 0;

    if (nparts > 0){
        int ql = t & 15, g = t >> 4;
        int per = nparts >> 6;
        uint32_t c[16];
        #pragma unroll
        for (int k = 0; k < 16; ++k) c[k] = 0;
        const uint4* base4 = (const uint4*)partials;
        size_t qoff = (size_t)b * 16 + ql;
        for (int j = 0; j < per; ++j){
            uint4 v = base4[(size_t)(g * per + j) * (HIST_WORDS8 / 4) + qoff];
            c[ 0] += v.x & 255u; c[ 1] += (v.x >> 8) & 255u; c[ 2] += (v.x >> 16) & 255u; c[ 3] += v.x >> 24;
            c[ 4] += v.y & 255u; c[ 5] += (v.y >> 8) & 255u; c[ 6] += (v.y >> 16) & 255u; c[ 7] += v.y >> 24;
            c[ 8] += v.z & 255u; c[ 9] += (v.z >> 8) & 255u; c[10] += (v.z >> 16) & 255u; c[11] += v.z >> 24;
            c[12] += v.w & 255u; c[13] += (v.w >> 8) & 255u; c[14] += (v.w >> 16) & 255u; c[15] += v.w >> 24;
        }
        #pragma unroll
        for (int k = 0; k < 16; ++k) sm[g][k][ql] = c[k];
        __syncthreads();
        if (t < 256){
            int q2 = t & 15, k = t >> 4;
            uint32_t s = 0;
            #pragma unroll 8
            for (int gg = 0; gg < 64; ++gg) s += sm[gg][k][q2];
            cnt = s;   // bin column q2*16+k == col
        }
    } else {
        if (t < 256) cnt = ghist[b * 256 + col];
    }
    __syncthreads();   // sm reads complete before scratch reuse

    // rsum_b = sum of row b
    uint32_t r = cnt;
    #pragma unroll
    for (int o = 32; o > 0; o >>= 1) r += __shfl_down(r, o, 64);
    if ((t & 63) == 0) flat[t >> 6] = r;
    __syncthreads();
    uint32_t rsum_b = 0;
    #pragma unroll
    for (int w = 0; w < 16; ++w) rsum_b += flat[w];

    if (t < 256) atomicAdd(&csum[col], cnt);   // device-scope
    grid.sync();

    if (t < 256) lcs[t] = __hip_atomic_load(&csum[t], __ATOMIC_RELAXED, __HIP_MEMORY_SCOPE_AGENT);
    __syncthreads();

    const double invn = 1.0 / (double)n, dn = (double)n;
    double mi = 0.0;
    if (t < 256 && cnt){
        double ratio = ((double)cnt * dn) / ((double)rsum_b * (double)lcs[col]);
        mi = (double)cnt * (double)logf((float)ratio);
    }
    #pragma unroll
    for (int o = 32; o > 0; o >>= 1) mi += __shfl_down(mi, o, 64);
    if ((t & 63) == 0) dred[t >> 6] = mi;
    __syncthreads();
    if (t == 0){
        double mis = 0.0;
        for (int w = 0; w < 16; ++w) mis += dred[w];
        mis *= invn;
        double px = (double)rsum_b * invn;
        double hx = px * log(px + 1e-8);
        double py = (double)lcs[b] * invn;
        double hy = py * log(py + 1e-8);
        __hip_atomic_store(&dslots[3*b+0], mis, __ATOMIC_RELAXED, __HIP_MEMORY_SCOPE_AGENT);
        __hip_atomic_store(&dslots[3*b+1], hx,  __ATOMIC_RELAXED, __HIP_MEMORY_SCOPE_AGENT);
        __hip_atomic_store(&dslots[3*b+2], hy,  __ATOMIC_RELAXED, __HIP_MEMORY_SCOPE_AGENT);
    }
    grid.sync();

    if (b == 0){
        double vmi = 0.0, vhx = 0.0, vhy = 0.0;
        if (t < 256){
            vmi = __hip_atomic_load(&dslots[3*t+0], __ATOMIC_RELAXED, __HIP_MEMORY_SCOPE_AGENT);
            vhx = __hip_atomic_load(&dslots[3*t+1], __ATOMIC_RELAXED, __HIP_MEMORY_SCOPE_AGENT);
            vhy = __hip_atomic_load(&dslots[3*t+2], __ATOMIC_RELAXED, __HIP_MEMORY_SCOPE_AGENT);
        }
        #pragma unroll
        for (int o = 32; o > 0; o >>= 1){
            vmi += __shfl_down(vmi, o, 64);
            vhx += __shfl_down(vhx, o, 64);
            vhy += __shfl_down(vhy, o, 64);
        }
        __syncthreads();
        if ((t & 63) == 0){
            dred[t >> 6]      = vmi;
            dred[16 + (t >> 6)] = vhx;
            dred[32 + (t >> 6)] = vhy;
        }
        __syncthreads();
        if (t == 0){
            double mi_s = 0.0, hx_s = 0.0, hy_s = 0.0;
            for (int w = 0; w < 16; ++w){
                mi_s += dred[w]; hx_s += dred[16 + w]; hy_s += dred[32 + w];
            }
            double h_x = -hx_s, h_y = -hy_s;
            double nmi = mi_s / (sqrt(h_x * h_y) + 1e-8);
            out[0] = (float)(-nmi);
        }
    }
}

extern "C" void kernel_launch(void* const* d_in, const int* in_sizes, int n_in,
                              void* d_out, int out_size, void* d_ws, size_t ws_size,
                              hipStream_t stream){
    const f4* x = (const f4*)d_in[0];
    const f4* y = (const f4*)d_in[1];
    float* out = (float*)d_out;
    uint32_t* ws = (uint32_t*)d_ws;
    float2*   slots  = (float2*)ws;            // words [0,1024)
    uint32_t* csum   = ws + 1024;              // words [1024,1280)
    double*   dslots = (double*)(ws + 1280);   // words [1280,2816)
    uint32_t* ghist  = ws + 4096;              // fallback-only (aliases partials)
    uint32_t* partials = ws + 4096;

    int n  = in_sizes[0];
    int n4 = n / 4;

    size_t need512 = ((size_t)4096 + (size_t)512 * HIST_WORDS8) * 4;
    size_t need256 = ((size_t)4096 + (size_t)256 * HIST_WORDS8) * 4;
    int nblk, atomic_flush, nparts;
    if (ws_size >= need512)      { nblk = 512; atomic_flush = 0; nparts = 512; }
    else if (ws_size >= need256) { nblk = 256; atomic_flush = 0; nparts = 256; }
    else                         { nblk = 512; atomic_flush = 1; nparts = 0;   }

    if (atomic_flush)
        hipMemsetAsync(ghist, 0, 65536 * sizeof(uint32_t), stream);
    minmax_kernel<<<512, 1024, 0, stream>>>(x, y, slots, n4, 256);
    hist_kernel<<<nblk, 1024, 0, stream>>>(x, y, slots, csum,
                                           atomic_flush ? ghist : partials, n4, atomic_flush);
    const uint32_t* pp = partials;
    const uint32_t* gh = ghist;
    void* args[] = { (void*)&pp, (void*)&gh, (void*)&csum, (void*)&dslots,
                     (void*)&out, (void*)&n, (void*)&nparts };
    hipLaunchCooperativeKernel((const void*)reduce_finalize_kernel,
                               dim3(256), dim3(1024), args, 0, stream);
}